// Round 15
// baseline (244.274 us; speedup 1.0000x reference)
//
#include <hip/hip_runtime.h>
#include <math.h>

#define BATCH 128
#define NR 2312          // 8*17*17 routes
#define RC 34            // route chunk (k_s)
#define NCH 68           // NR / RC
#define NC 10            // caps
#define K1 352           // conv1 padded K: (ci*9+kh)*12 + kw

typedef short short8 __attribute__((ext_vector_type(8)));
typedef float f32x4 __attribute__((ext_vector_type(4)));
typedef unsigned long long u64;

// ---- workspace layout (float-slot offsets) ----
#define OFF_XH    0                        // bf16[128][1681][32] = 3442688 floats
#define OFF_XTB   3442688                  // bf16[2320][128][8] = 1187840 floats
#define OFF_SC    4630528                  // 1024 (raw sum-of-squares per (b,i))
#define OFF_BIJ   4631552                  // 23120
#define OFF_SP    4654672                  // 68*10*128*16 = 1392640, layout [ch][c][b][o]
#define OFF_V     6047312                  // 20480
#define OFF_WB    6067792                  // bf16[81][4][16][32] = 82944 floats
#define OFF_VT    6150736                  // 10*16*128 = 20480
#define OFF_W1    6171216                  // bf16[32][352] = 5632 floats
// end: 6176848 floats = 24.7 MB

__device__ __forceinline__ unsigned short f2bf(float f) {
    unsigned int u = __float_as_uint(f);
    u = (u + 0x7FFFu + ((u >> 16) & 1u)) >> 16;   // RNE
    return (unsigned short)u;
}
__device__ __forceinline__ float bf2f(unsigned short h) {
    return __uint_as_float(((unsigned int)h) << 16);
}

// fused prep: Wb (conv2 weights bf16), bij zero, scale zero, W1 (conv1 weights bf16)
// NOTE: routing weights Wd stay fp32 — bf16 W in the k_a->bij feedback path
// amplifies through softmax across iterations (R14 failed at 3.6e-2).
__global__ void k_prep(const float* __restrict__ cw, const float* __restrict__ pw,
                       unsigned short* __restrict__ W1, unsigned short* __restrict__ Wb,
                       float* __restrict__ bij, float* __restrict__ scale) {
    int idx = blockIdx.x * 256 + threadIdx.x;
    if (idx < 165888) {
        int ci = idx & 31, co = (idx >> 5) & 15, cog = (idx >> 9) & 3, tap = idx >> 11;
        Wb[idx] = f2bf(pw[((cog * 16 + co) * 32 + ci) * 81 + tap]);
        return;
    }
    idx -= 165888;
    if (idx < 23120) { bij[idx] = 0.f; return; }
    idx -= 23120;
    if (idx < 1024) { scale[idx] = 0.f; return; }
    idx -= 1024;
    if (idx < 32 * K1) {
        int co = idx / K1, k = idx - co * K1;
        int g = k / 12, kw = k - g * 12;
        float v = (kw < 9 && g < 27) ? cw[((co * 3 + g / 9) * 9 + (g % 9)) * 9 + kw] : 0.f;
        W1[idx] = f2bf(v);
    }
}

// conv1 via im2col-in-LDS MFMA: data fp32 -> xh bf16 [b][p][co=32] (+bias+relu)
__global__ __launch_bounds__(512) void k_conv1m(const float* __restrict__ data,
                                                const unsigned short* __restrict__ W1,
                                                const float* __restrict__ cb,
                                                unsigned short* __restrict__ xh) {
    int b = blockIdx.x / 27, g64 = blockIdx.x % 27;
    int p0 = g64 * 64;
    int t = threadIdx.x, lane = t & 63, wv = t >> 6;      // wv 0..7
    int quad = lane >> 4, mloc = lane & 15;
    int msub = wv & 3, chh = wv >> 2;
    __shared__ __align__(16) unsigned short As[88 * 64 * 4];   // 45056 B
    u64* ab = (u64*)As;
    for (int k = 81 * 64 + t; k < 88 * 64; k += 512) ab[k] = 0ull;
#pragma unroll 1
    for (int it = 0; it < 4; it++) {
        int g = wv + it * 8;
        if (g < 27) {
            int m = lane;
            int p = p0 + m; if (p > 1680) p = 1680;
            int h = p / 41, w = p - h * 41;
            int ci = g / 9, kh = g - ci * 9;
            const float* src = &data[((b * 3 + ci) * 49 + (h + kh)) * 49 + w];
            unsigned short pk[12];
#pragma unroll
            for (int kw = 0; kw < 9; kw++) pk[kw] = f2bf(src[kw]);
            pk[9] = 0; pk[10] = 0; pk[11] = 0;
            const u64* s = (const u64*)pk;
            ab[(3 * g + 0) * 64 + m] = s[0];
            ab[(3 * g + 1) * 64 + m] = s[1];
            ab[(3 * g + 2) * 64 + m] = s[2];
        }
    }
    __syncthreads();
    f32x4 acc = {0.f, 0.f, 0.f, 0.f};
    const unsigned short* wp = &W1[(size_t)(chh * 16 + mloc) * K1 + quad * 8];
    int mrow = msub * 16 + mloc;
#pragma unroll 1
    for (int kc = 0; kc < 11; kc++) {
        int c = kc * 8 + quad * 2;
        union { short8 v; u64 q[2]; } af;
        af.q[0] = ab[c * 64 + mrow];
        af.q[1] = ab[(c + 1) * 64 + mrow];
        short8 bfr = *(const short8*)(wp + kc * 32);
        acc = __builtin_amdgcn_mfma_f32_16x16x32_bf16(af.v, bfr, acc, 0, 0, 0);
    }
    __syncthreads();
    unsigned short* tile = As;                    // reuse: [64 m][40]
    float bias = cb[chh * 16 + mloc];
#pragma unroll
    for (int r = 0; r < 4; r++) {
        int m = msub * 16 + quad * 4 + r;
        float v0 = acc[r] + bias; v0 = v0 > 0.f ? v0 : 0.f;
        tile[m * 40 + chh * 16 + mloc] = f2bf(v0);
    }
    __syncthreads();
    if (t < 256) {
        int m = t >> 2, part = t & 3;
        int p = p0 + m;
        if (p < 1681)
            *(int4*)&xh[((size_t)(b * 1681 + p)) * 32 + part * 8] =
                *(const int4*)&tile[m * 40 + part * 8];
    }
}

// conv2 implicit-GEMM MFMA -> xTb bf16 directly (+ sumsq into scale).
// R11-proven geometry: grid 640 = (b, g of 64 positions), 17-row A-tile,
// 8 waves = 4 cg x 2 position-halves, 2 m-tiles/wave, 64x65 epilogue tile.
// A-tile parity-split cols (e = even: col/2, odd: 21+col/2), stride 36 shorts.
__global__ __launch_bounds__(512) void k_conv2(const unsigned short* __restrict__ xh,
                                               const unsigned short* __restrict__ Wb,
                                               const float* __restrict__ pb,
                                               unsigned short* __restrict__ xTb,
                                               float* __restrict__ scale) {
    int b = blockIdx.x / 5, g = blockIdx.x % 5;
    int t = threadIdx.x, lane = t & 63, wv = t >> 6;
    int quad = lane >> 4, mloc = lane & 15;
    int cg = wv & 3, half = wv >> 2;
    __shared__ __align__(16) char lds[50184];     // max(17*41*36*2, 64*65*4)
    __shared__ float pbs[64];
    unsigned short* As = (unsigned short*)lds;
    if (t < 64) pbs[t] = pb[t];
    const unsigned short* xb = xh + (size_t)b * 53792;   // 1681*32
    int p_hi = g * 64 + 63; if (p_hi > 288) p_hi = 288;
    int r0 = 2 * ((g * 64) / 17);
    int nrows = 2 * (p_hi / 17) + 9 - r0;         // <= 17
    int nch = nrows * 164;                        // 8-short chunks: 41*4 per row
    for (int k = t; k < nch; k += 512) {
        int rl = k / 164, rem = k - rl * 164;
        int col = rem >> 2, ci8 = rem & 3;
        int e = (col & 1) ? 21 + (col >> 1) : (col >> 1);
        const u64* src = (const u64*)&xb[((r0 + rl) * 41 + col) * 32 + ci8 * 8];
        u64* dst = (u64*)&As[(rl * 41 + e) * 36 + ci8 * 8];
        dst[0] = src[0];
        dst[1] = src[1];
    }
    __syncthreads();
    int abase0, abase1;
    {
        int p = g * 64 + half * 32 + mloc;        // mt=0
        if (p > 288) p = 288;
        abase0 = ((2 * (p / 17) - r0) * 41 + (p % 17)) * 36 + quad * 8;
        p = g * 64 + half * 32 + 16 + mloc;       // mt=1
        if (p > 288) p = 288;
        abase1 = ((2 * (p / 17) - r0) * 41 + (p % 17)) * 36 + quad * 8;
    }
    const unsigned short* wbase = Wb + ((size_t)cg * 16 + mloc) * 32 + quad * 8;
    f32x4 acc0 = {0.f, 0.f, 0.f, 0.f}, acc1 = {0.f, 0.f, 0.f, 0.f};
#pragma unroll 1
    for (int kh = 0; kh < 9; kh++) {
        const unsigned short* wrow = wbase + (size_t)kh * 9 * 2048;
#pragma unroll
        for (int kw = 0; kw < 9; kw++) {
            short8 bf = *(const short8*)(wrow + (size_t)kw * 2048);
            int c0 = (kw & 1) ? 21 + (kw >> 1) : (kw >> 1);
            int off = (kh * 41 + c0) * 36;
            union { short8 v; u64 q[2]; } a0, a1;
            a0.q[0] = *(const u64*)&As[abase0 + off];
            a0.q[1] = *(const u64*)&As[abase0 + off + 4];
            a1.q[0] = *(const u64*)&As[abase1 + off];
            a1.q[1] = *(const u64*)&As[abase1 + off + 4];
            acc0 = __builtin_amdgcn_mfma_f32_16x16x32_bf16(a0.v, bf, acc0, 0, 0, 0);
            acc1 = __builtin_amdgcn_mfma_f32_16x16x32_bf16(a1.v, bf, acc1, 0, 0, 0);
        }
    }
    __syncthreads();                              // done reading A-tile
    float* tile = (float*)lds;                    // [64 ch][65]
#pragma unroll
    for (int r = 0; r < 4; r++) {
        tile[(cg * 16 + mloc) * 65 + half * 32 + quad * 4 + r] = acc0[r];
        tile[(cg * 16 + mloc) * 65 + half * 32 + 16 + quad * 4 + r] = acc1[r];
    }
    __syncthreads();
    // epilogue: t -> (pp = t>>3, j = t&7); pack 8 i's, write xTb, sumsq per i
    float ssq[8] = {0.f, 0.f, 0.f, 0.f, 0.f, 0.f, 0.f, 0.f};
    {
        int pp = t >> 3, j = t & 7;
        int p = g * 64 + pp;
        if (p < 289) {
            unsigned short pk[8];
#pragma unroll
            for (int i = 0; i < 8; i++) {
                float val = tile[(i * 8 + j) * 65 + pp] + pbs[i * 8 + j];
                pk[i] = f2bf(val);
                ssq[i] += val * val;
            }
            *(int4*)&xTb[((size_t)(j * 289 + p) * 128 + b) * 8] = *(const int4*)pk;
        }
    }
#pragma unroll
    for (int i = 0; i < 8; i++) {
        float s = ssq[i];
#pragma unroll
        for (int d = 1; d < 64; d <<= 1) s += __shfl_xor(s, d);
        if (lane == 0) atomicAdd(&scale[b * 8 + i], s);
    }
}

// in-place squash scale: xTb[r][b][i] *= sn/((1+sn)sqrt(sn)), sn = scale[b*8+i]
__global__ __launch_bounds__(256) void k_xt(unsigned short* __restrict__ xTb,
                                            const float* __restrict__ scale) {
    __shared__ float fs[1024];
    int t = threadIdx.x;
    for (int k = t; k < 1024; k += 256) {
        float sn = scale[k];
        fs[k] = sn / ((1.f + sn) * sqrtf(sn));
    }
    __syncthreads();
    int idx = blockIdx.x * 256 + t;               // (r,b), 2312*128 exact
    int b = idx & 127;
    unsigned short* p = &xTb[(size_t)idx * 8];
    union { int4 v; unsigned short u[8]; } d;
    d.v = *(const int4*)p;
#pragma unroll
    for (int i = 0; i < 8; i++) d.u[i] = f2bf(bf2f(d.u[i]) * fs[b * 8 + i]);
    *(int4*)p = d.v;
}

// s partials via MFMA (softmax fused): block (chunk of 34 r, c)
// spart layout: [chunk][c][b][o]
__global__ __launch_bounds__(256) void k_s(const unsigned short* __restrict__ xTb,
                                           const float* __restrict__ W,
                                           const float* __restrict__ bij,
                                           float* __restrict__ spart) {
    int chunk = blockIdx.x / NC, c = blockIdx.x % NC;
    int r0 = chunk * RC;
    __shared__ __align__(16) unsigned short As[16 * 296];   // 9472 B
    __shared__ float cs[RC];
    int t = threadIdx.x;
    { int o = t >> 4, kk = t & 15; As[o * 296 + 272 + kk] = 0; }  // zero pad k 272..287
    if (t < RC) {
        int r = r0 + t;
        float x[NC], m = -1e30f;
#pragma unroll
        for (int k = 0; k < NC; k++) { x[k] = bij[r * NC + k]; m = fmaxf(m, x[k]); }
        float s = 0.f;
#pragma unroll
        for (int k = 0; k < NC; k++) { x[k] = expf(x[k] - m); s += x[k]; }
        cs[t] = x[c] / s;
    }
    __syncthreads();
    for (int k = t; k < RC * 16; k += 256) {
        int rr = k >> 4, o = k & 15;
        const float* wsrc = &W[(size_t)(r0 + rr) * 1280 + c * 128 + o * 8];
        float cr = cs[rr];
        unsigned short pk[8];
#pragma unroll
        for (int i = 0; i < 8; i++) pk[i] = f2bf(wsrc[i] * cr);
        *(int4*)&As[o * 296 + rr * 8] = *(const int4*)pk;
    }
    __syncthreads();
    int lane = t & 63, wv = t >> 6;
    int quad = lane >> 4, mloc = lane & 15;
    int n0 = wv * 32;
    f32x4 acc0 = {0.f, 0.f, 0.f, 0.f}, acc1 = {0.f, 0.f, 0.f, 0.f};
    const unsigned short* ap = &As[mloc * 296 + quad * 8];
#pragma unroll
    for (int kc = 0; kc < 9; kc++) {
        short8 af = *(const short8*)(ap + kc * 32);
        const unsigned short* bb = &xTb[(size_t)(r0 + kc * 4 + quad) * 1024];
        short8 b0 = *(const short8*)(bb + (n0 + mloc) * 8);
        short8 b1 = *(const short8*)(bb + (n0 + 16 + mloc) * 8);
        acc0 = __builtin_amdgcn_mfma_f32_16x16x32_bf16(af, b0, acc0, 0, 0, 0);
        acc1 = __builtin_amdgcn_mfma_f32_16x16x32_bf16(af, b1, acc1, 0, 0, 0);
    }
    float* sp = &spart[(size_t)(chunk * NC + c) * 2048];   // [b][o]
    *(f32x4*)&sp[(n0 + mloc) * 16 + quad * 4] = acc0;
    *(f32x4*)&sp[(n0 + 16 + mloc) * 16 + quad * 4] = acc1;
}

// reduce spart over chunks, squash -> v, vT, out; fused head on last iteration.
// grid 1280 = (b,c); 256 thr = 16 chunk-lanes x 16 o.
__global__ __launch_bounds__(256) void k_v(const float* __restrict__ spart,
                    float* __restrict__ v, float* __restrict__ vT,
                    float* __restrict__ out,
                    const float* __restrict__ w1, const float* __restrict__ b1,
                    const float* __restrict__ w2, const float* __restrict__ b2,
                    int do_head) {
    int b = blockIdx.x / NC, c = blockIdx.x % NC;
    int t = threadIdx.x;
    int cl = t >> 4, o = t & 15;
    float s = 0.f;
#pragma unroll 1
    for (int ch = cl; ch < NCH; ch += 16)
        s += spart[((size_t)(ch * NC + c) * 128 + b) * 16 + o];
    s += __shfl_xor(s, 16);
    s += __shfl_xor(s, 32);
    __shared__ float red[4][16];
    __shared__ float hred[2];
    if ((t & 63) < 16) red[t >> 6][t & 15] = s;
    __syncthreads();
    if (t < 16) {
        float sum = red[0][t] + red[1][t] + red[2][t] + red[3][t];
        float sq = sum * sum;
#pragma unroll
        for (int d = 1; d < 16; d <<= 1) sq += __shfl_xor(sq, d);
        float vv = sum * sq / ((1.f + sq) * sqrtf(sq));
        int idx = (b * NC + c) * 16 + t;
        v[idx] = vv;
        out[idx] = vv;
        vT[(c * 16 + t) * 128 + b] = vv;
        red[0][t] = vv;
    }
    if (do_head) {
        __syncthreads();
        float partial = 0.f;
        if (t < 100) {
            float hs = b1[c * 100 + t];
#pragma unroll
            for (int i = 0; i < 16; i++) hs = fmaf(red[0][i], w1[(c * 16 + i) * 100 + t], hs);
            partial = tanhf(hs) * w2[c * 100 + t];
        }
#pragma unroll
        for (int d = 1; d < 64; d <<= 1) partial += __shfl_xor(partial, d);
        if ((t & 63) == 0 && t < 128) hred[t >> 6] = partial;
        __syncthreads();
        if (t == 0)
            out[20480 + c * 128 + b] = 1.f / (1.f + expf(-(hred[0] + hred[1] + b2[c])));
    }
}

// a[r,c] = 1/B * sum_{b,o} vT[c,o,b] * sum_i W[r,c,o,i]*xTb[r,b,i];  bij += a
// fp32 W: this path feeds back into bij logits (bf16 here fails — R14).
__global__ __launch_bounds__(256) void k_a(const unsigned short* __restrict__ xTb,
                                           const float* __restrict__ W,
                                           const float* __restrict__ vT,
                                           float* __restrict__ bij) {
    int wv = threadIdx.x >> 6, lane = threadIdx.x & 63;
    int wid = __builtin_amdgcn_readfirstlane(blockIdx.x * 4 + wv);
    int r = wid / NC, c = wid - r * NC;
    const unsigned short* xr = &xTb[(size_t)r * 1024];
    union { short8 v; unsigned short u[8]; } s0, s1;
    s0.v = *(const short8*)(xr + lane * 8);
    s1.v = *(const short8*)(xr + (lane + 64) * 8);
    float x0[8], x1[8];
#pragma unroll
    for (int i = 0; i < 8; i++) { x0[i] = bf2f(s0.u[i]); x1[i] = bf2f(s1.u[i]); }
    const float* wr = &W[(size_t)r * 1280 + c * 128];
    const float* vc = &vT[c * 2048];
    float acc = 0.f;
#pragma unroll
    for (int o = 0; o < 16; o++) {
        float w[8];
#pragma unroll
        for (int i = 0; i < 8; i++) w[i] = wr[o * 8 + i];
        float u0 = 0.f, u1 = 0.f;
#pragma unroll
        for (int i = 0; i < 8; i++) { u0 = fmaf(w[i], x0[i], u0); u1 = fmaf(w[i], x1[i], u1); }
        acc = fmaf(vc[o * 128 + lane], u0, acc);
        acc = fmaf(vc[o * 128 + lane + 64], u1, acc);
    }
#pragma unroll
    for (int d = 1; d < 64; d <<= 1) acc += __shfl_xor(acc, d);
    if (lane == 0) bij[wid] += acc * 0.0078125f;
}

extern "C" void kernel_launch(void* const* d_in, const int* in_sizes, int n_in,
                              void* d_out, int out_size, void* d_ws, size_t ws_size,
                              hipStream_t stream) {
    const float* data   = (const float*)d_in[0];
    const float* conv_w = (const float*)d_in[1];
    const float* conv_b = (const float*)d_in[2];
    const float* prim_w = (const float*)d_in[3];
    const float* prim_b = (const float*)d_in[4];
    const float* Wd     = (const float*)d_in[5];
    const float* hw1    = (const float*)d_in[6];
    const float* hb1    = (const float*)d_in[7];
    const float* hw2    = (const float*)d_in[8];
    const float* hb2    = (const float*)d_in[9];
    float* ws = (float*)d_ws;
    unsigned short* xh  = (unsigned short*)(ws + OFF_XH);
    unsigned short* xTb = (unsigned short*)(ws + OFF_XTB);
    float* scale = ws + OFF_SC;
    float* bij   = ws + OFF_BIJ;
    float* spart = ws + OFF_SP;
    float* v     = ws + OFF_V;
    unsigned short* Wb  = (unsigned short*)(ws + OFF_WB);
    float* vT    = ws + OFF_VT;
    unsigned short* W1  = (unsigned short*)(ws + OFF_W1);
    float* out = (float*)d_out;

    k_prep<<<787, 256, 0, stream>>>(conv_w, prim_w, W1, Wb, bij, scale);
    k_conv1m<<<128 * 27, 512, 0, stream>>>(data, W1, conv_b, xh);
    k_conv2<<<128 * 5, 512, 0, stream>>>(xh, Wb, prim_b, xTb, scale);
    k_xt<<<1156, 256, 0, stream>>>(xTb, scale);
    for (int it = 0; it < 3; it++) {
        k_s<<<NCH * NC, 256, 0, stream>>>(xTb, Wd, bij, spart);
        k_v<<<128 * NC, 256, 0, stream>>>(spart, v, vT, out, hw1, hb1, hw2, hb2,
                                          it == 2 ? 1 : 0);
        if (it < 2) k_a<<<5780, 256, 0, stream>>>(xTb, Wd, vT, bij);
    }
}

// Round 16
// 237.327 us; speedup vs baseline: 1.0293x; 1.0293x over previous
//
#include <hip/hip_runtime.h>
#include <math.h>

#define BATCH 128
#define NR 2312          // 8*17*17 routes
#define RC 34            // route chunk (k_s)
#define NCH 68           // NR / RC
#define NC 10            // caps
#define K1 352           // conv1 padded K: (ci*9+kh)*12 + kw

typedef short short8 __attribute__((ext_vector_type(8)));
typedef float f32x4 __attribute__((ext_vector_type(4)));
typedef unsigned long long u64;

// ---- workspace layout (float-slot offsets) ----
#define OFF_XH    0                        // bf16[128][1681][32] = 3442688 floats
#define OFF_U0    3442688                  // 128*64*289 = 2367488
#define OFF_XTB   5810176                  // bf16[2320][128][8] = 1187840 floats
#define OFF_SC    6998016                  // 1024 (raw sum-of-squares per (b,i))
#define OFF_BIJ   6999040                  // 23120
#define OFF_SP    7022160                  // 68*10*128*16 = 1392640, layout [ch][c][b][o]
#define OFF_V     8414800                  // 20480
#define OFF_WB    8435280                  // bf16[81][4][16][32] = 82944 floats
#define OFF_VT    8518224                  // 10*16*128 = 20480
#define OFF_W1    8538704                  // bf16[32][352] = 5632 floats
// end: 8544336 floats = 34.2 MB

__device__ __forceinline__ unsigned short f2bf(float f) {
    unsigned int u = __float_as_uint(f);
    u = (u + 0x7FFFu + ((u >> 16) & 1u)) >> 16;   // RNE
    return (unsigned short)u;
}
__device__ __forceinline__ float bf2f(unsigned short h) {
    return __uint_as_float(((unsigned int)h) << 16);
}

// fused prep: Wb (conv2 weights bf16), bij zero, scale zero, W1 (conv1 weights bf16)
// Routing weights Wd stay fp32 (bf16 in the k_a->bij feedback path fails — R14).
__global__ void k_prep(const float* __restrict__ cw, const float* __restrict__ pw,
                       unsigned short* __restrict__ W1, unsigned short* __restrict__ Wb,
                       float* __restrict__ bij, float* __restrict__ scale) {
    int idx = blockIdx.x * 256 + threadIdx.x;
    if (idx < 165888) {
        int ci = idx & 31, co = (idx >> 5) & 15, cog = (idx >> 9) & 3, tap = idx >> 11;
        Wb[idx] = f2bf(pw[((cog * 16 + co) * 32 + ci) * 81 + tap]);
        return;
    }
    idx -= 165888;
    if (idx < 23120) { bij[idx] = 0.f; return; }
    idx -= 23120;
    if (idx < 1024) { scale[idx] = 0.f; return; }
    idx -= 1024;
    if (idx < 32 * K1) {
        int co = idx / K1, k = idx - co * K1;
        int g = k / 12, kw = k - g * 12;
        float v = (kw < 9 && g < 27) ? cw[((co * 3 + g / 9) * 9 + (g % 9)) * 9 + kw] : 0.f;
        W1[idx] = f2bf(v);
    }
}

// conv1 via im2col-in-LDS MFMA: data fp32 -> xh bf16 [b][p][co=32] (+bias+relu)
__global__ __launch_bounds__(512) void k_conv1m(const float* __restrict__ data,
                                                const unsigned short* __restrict__ W1,
                                                const float* __restrict__ cb,
                                                unsigned short* __restrict__ xh) {
    int b = blockIdx.x / 27, g64 = blockIdx.x % 27;
    int p0 = g64 * 64;
    int t = threadIdx.x, lane = t & 63, wv = t >> 6;      // wv 0..7
    int quad = lane >> 4, mloc = lane & 15;
    int msub = wv & 3, chh = wv >> 2;
    __shared__ __align__(16) unsigned short As[88 * 64 * 4];   // 45056 B
    u64* ab = (u64*)As;
    for (int k = 81 * 64 + t; k < 88 * 64; k += 512) ab[k] = 0ull;
#pragma unroll 1
    for (int it = 0; it < 4; it++) {
        int g = wv + it * 8;
        if (g < 27) {
            int m = lane;
            int p = p0 + m; if (p > 1680) p = 1680;
            int h = p / 41, w = p - h * 41;
            int ci = g / 9, kh = g - ci * 9;
            const float* src = &data[((b * 3 + ci) * 49 + (h + kh)) * 49 + w];
            unsigned short pk[12];
#pragma unroll
            for (int kw = 0; kw < 9; kw++) pk[kw] = f2bf(src[kw]);
            pk[9] = 0; pk[10] = 0; pk[11] = 0;
            const u64* s = (const u64*)pk;
            ab[(3 * g + 0) * 64 + m] = s[0];
            ab[(3 * g + 1) * 64 + m] = s[1];
            ab[(3 * g + 2) * 64 + m] = s[2];
        }
    }
    __syncthreads();
    f32x4 acc = {0.f, 0.f, 0.f, 0.f};
    const unsigned short* wp = &W1[(size_t)(chh * 16 + mloc) * K1 + quad * 8];
    int mrow = msub * 16 + mloc;
#pragma unroll 1
    for (int kc = 0; kc < 11; kc++) {
        int c = kc * 8 + quad * 2;
        union { short8 v; u64 q[2]; } af;
        af.q[0] = ab[c * 64 + mrow];
        af.q[1] = ab[(c + 1) * 64 + mrow];
        short8 bfr = *(const short8*)(wp + kc * 32);
        acc = __builtin_amdgcn_mfma_f32_16x16x32_bf16(af.v, bfr, acc, 0, 0, 0);
    }
    __syncthreads();
    unsigned short* tile = As;                    // reuse: [64 m][40]
    float bias = cb[chh * 16 + mloc];
#pragma unroll
    for (int r = 0; r < 4; r++) {
        int m = msub * 16 + quad * 4 + r;
        float v0 = acc[r] + bias; v0 = v0 > 0.f ? v0 : 0.f;
        tile[m * 40 + chh * 16 + mloc] = f2bf(v0);
    }
    __syncthreads();
    if (t < 256) {
        int m = t >> 2, part = t & 3;
        int p = p0 + m;
        if (p < 1681)
            *(int4*)&xh[((size_t)(b * 1681 + p)) * 32 + part * 8] =
                *(const int4*)&tile[m * 40 + part * 8];
    }
}

// conv2 implicit-GEMM MFMA (R11-proven, 44.8 us): grid 640 = (b, g of 64 pos),
// 17-row parity-split A-tile, 8 waves = 4 cg x 2 position-halves, coalesced
// u0 fp32 output + fused per-(b,i) sumsq atomic.
__global__ __launch_bounds__(512) void k_conv2(const unsigned short* __restrict__ xh,
                                               const unsigned short* __restrict__ Wb,
                                               const float* __restrict__ pb,
                                               float* __restrict__ u0,
                                               float* __restrict__ scale) {
    int b = blockIdx.x / 5, g = blockIdx.x % 5;
    int t = threadIdx.x, lane = t & 63, wv = t >> 6;
    int quad = lane >> 4, mloc = lane & 15;
    int cg = wv & 3, half = wv >> 2;
    __shared__ __align__(16) char lds[50184];     // max(17*41*36*2, 64*65*4)
    unsigned short* As = (unsigned short*)lds;
    const unsigned short* xb = xh + (size_t)b * 53792;   // 1681*32
    int p_hi = g * 64 + 63; if (p_hi > 288) p_hi = 288;
    int r0 = 2 * ((g * 64) / 17);
    int nrows = 2 * (p_hi / 17) + 9 - r0;         // <= 17
    int nch = nrows * 164;                        // 8-short chunks: 41*4 per row
    for (int k = t; k < nch; k += 512) {
        int rl = k / 164, rem = k - rl * 164;
        int col = rem >> 2, ci8 = rem & 3;
        int e = (col & 1) ? 21 + (col >> 1) : (col >> 1);
        const u64* src = (const u64*)&xb[((r0 + rl) * 41 + col) * 32 + ci8 * 8];
        u64* dst = (u64*)&As[(rl * 41 + e) * 36 + ci8 * 8];
        dst[0] = src[0];
        dst[1] = src[1];
    }
    __syncthreads();
    int abase0, abase1;
    {
        int p = g * 64 + half * 32 + mloc;        // mt=0
        if (p > 288) p = 288;
        abase0 = ((2 * (p / 17) - r0) * 41 + (p % 17)) * 36 + quad * 8;
        p = g * 64 + half * 32 + 16 + mloc;       // mt=1
        if (p > 288) p = 288;
        abase1 = ((2 * (p / 17) - r0) * 41 + (p % 17)) * 36 + quad * 8;
    }
    const unsigned short* wbase = Wb + ((size_t)cg * 16 + mloc) * 32 + quad * 8;
    f32x4 acc0 = {0.f, 0.f, 0.f, 0.f}, acc1 = {0.f, 0.f, 0.f, 0.f};
#pragma unroll 1
    for (int kh = 0; kh < 9; kh++) {
        const unsigned short* wrow = wbase + (size_t)kh * 9 * 2048;
#pragma unroll
        for (int kw = 0; kw < 9; kw++) {
            short8 bf = *(const short8*)(wrow + (size_t)kw * 2048);
            int c0 = (kw & 1) ? 21 + (kw >> 1) : (kw >> 1);
            int off = (kh * 41 + c0) * 36;
            union { short8 v; u64 q[2]; } a0, a1;
            a0.q[0] = *(const u64*)&As[abase0 + off];
            a0.q[1] = *(const u64*)&As[abase0 + off + 4];
            a1.q[0] = *(const u64*)&As[abase1 + off];
            a1.q[1] = *(const u64*)&As[abase1 + off + 4];
            acc0 = __builtin_amdgcn_mfma_f32_16x16x32_bf16(a0.v, bf, acc0, 0, 0, 0);
            acc1 = __builtin_amdgcn_mfma_f32_16x16x32_bf16(a1.v, bf, acc1, 0, 0, 0);
        }
    }
    __syncthreads();                              // done reading A-tile
    float* tile = (float*)lds;                    // [64 ch][65]
#pragma unroll
    for (int r = 0; r < 4; r++) {
        tile[(cg * 16 + mloc) * 65 + half * 32 + quad * 4 + r] = acc0[r];
        tile[(cg * 16 + mloc) * 65 + half * 32 + 16 + quad * 4 + r] = acc1[r];
    }
    __syncthreads();
    int co = t >> 3, p0w = (t & 7) * 8;
    float bias = pb[co];
    float ssum = 0.f;
#pragma unroll
    for (int j = 0; j < 8; j++) {
        int p = g * 64 + p0w + j;
        if (p < 289) {
            float val = tile[co * 65 + p0w + j] + bias;
            u0[((size_t)(b * 64 + co)) * 289 + p] = val;
            ssum += val * val;
        }
    }
    // wave wv covers co = wv*8..wv*8+7  ->  i = wv
#pragma unroll
    for (int d = 1; d < 64; d <<= 1) ssum += __shfl_xor(ssum, d);
    if (lane == 0) atomicAdd(&scale[b * 8 + wv], ssum);
}

// build xTb[r][b][i] (bf16) = u0[b][i*8+j][hw] * squash_scale(b,i)  (r = j*289+hw)
// block = (i, j, hw-tile of 32); grid 640.
__global__ __launch_bounds__(256) void k_xt(const float* __restrict__ u0,
                                            const float* __restrict__ scale,
                                            unsigned short* __restrict__ xTb) {
    int tid = blockIdx.x;
    int tile_i = tid / 10, hwt = tid % 10;
    int i = tile_i >> 3, j = tile_i & 7;
    int ch = i * 8 + j;
    int hw0 = hwt * 32;
    int rem = 289 - hw0; if (rem > 32) rem = 32;
    __shared__ float tile[32 * 130];
    __shared__ float sc_s[128];
    int t = threadIdx.x;
    if (t < 128) {
        float sn = scale[t * 8 + i];
        sc_s[t] = sn / ((1.f + sn) * sqrtf(sn));
    }
    for (int k = t; k < 32 * 128; k += 256) {
        int bb = k >> 5, x = k & 31;
        if (x < rem)
            tile[x * 130 + bb] = u0[(bb * 64 + ch) * 289 + hw0 + x];
    }
    __syncthreads();
    for (int k = t; k < 32 * 128; k += 256) {
        int hwl = k >> 7, bb = k & 127;
        if (hwl < rem)
            xTb[((size_t)((j * 289 + hw0 + hwl)) * 128 + bb) * 8 + i] =
                f2bf(tile[hwl * 130 + bb] * sc_s[bb]);
    }
}

// s partials via MFMA (softmax fused): block (chunk of 34 r, c)
// spart layout: [chunk][c][b][o]
__global__ __launch_bounds__(256) void k_s(const unsigned short* __restrict__ xTb,
                                           const float* __restrict__ W,
                                           const float* __restrict__ bij,
                                           float* __restrict__ spart) {
    int chunk = blockIdx.x / NC, c = blockIdx.x % NC;
    int r0 = chunk * RC;
    __shared__ __align__(16) unsigned short As[16 * 296];   // 9472 B
    __shared__ float cs[RC];
    int t = threadIdx.x;
    { int o = t >> 4, kk = t & 15; As[o * 296 + 272 + kk] = 0; }  // zero pad k 272..287
    if (t < RC) {
        int r = r0 + t;
        float x[NC], m = -1e30f;
#pragma unroll
        for (int k = 0; k < NC; k++) { x[k] = bij[r * NC + k]; m = fmaxf(m, x[k]); }
        float s = 0.f;
#pragma unroll
        for (int k = 0; k < NC; k++) { x[k] = expf(x[k] - m); s += x[k]; }
        cs[t] = x[c] / s;
    }
    __syncthreads();
    for (int k = t; k < RC * 16; k += 256) {
        int rr = k >> 4, o = k & 15;
        const float* wsrc = &W[(size_t)(r0 + rr) * 1280 + c * 128 + o * 8];
        float cr = cs[rr];
        unsigned short pk[8];
#pragma unroll
        for (int i = 0; i < 8; i++) pk[i] = f2bf(wsrc[i] * cr);
        *(int4*)&As[o * 296 + rr * 8] = *(const int4*)pk;
    }
    __syncthreads();
    int lane = t & 63, wv = t >> 6;
    int quad = lane >> 4, mloc = lane & 15;
    int n0 = wv * 32;
    f32x4 acc0 = {0.f, 0.f, 0.f, 0.f}, acc1 = {0.f, 0.f, 0.f, 0.f};
    const unsigned short* ap = &As[mloc * 296 + quad * 8];
#pragma unroll
    for (int kc = 0; kc < 9; kc++) {
        short8 af = *(const short8*)(ap + kc * 32);
        const unsigned short* bb = &xTb[(size_t)(r0 + kc * 4 + quad) * 1024];
        short8 b0 = *(const short8*)(bb + (n0 + mloc) * 8);
        short8 b1 = *(const short8*)(bb + (n0 + 16 + mloc) * 8);
        acc0 = __builtin_amdgcn_mfma_f32_16x16x32_bf16(af, b0, acc0, 0, 0, 0);
        acc1 = __builtin_amdgcn_mfma_f32_16x16x32_bf16(af, b1, acc1, 0, 0, 0);
    }
    float* sp = &spart[(size_t)(chunk * NC + c) * 2048];   // [b][o]
    *(f32x4*)&sp[(n0 + mloc) * 16 + quad * 4] = acc0;
    *(f32x4*)&sp[(n0 + 16 + mloc) * 16 + quad * 4] = acc1;
}

// reduce spart over chunks, squash -> v, vT, out; fused head on last iteration.
// grid 1280 = (b,c); 256 thr = 16 chunk-lanes x 16 o.
__global__ __launch_bounds__(256) void k_v(const float* __restrict__ spart,
                    float* __restrict__ v, float* __restrict__ vT,
                    float* __restrict__ out,
                    const float* __restrict__ w1, const float* __restrict__ b1,
                    const float* __restrict__ w2, const float* __restrict__ b2,
                    int do_head) {
    int b = blockIdx.x / NC, c = blockIdx.x % NC;
    int t = threadIdx.x;
    int cl = t >> 4, o = t & 15;
    float s = 0.f;
#pragma unroll 1
    for (int ch = cl; ch < NCH; ch += 16)
        s += spart[((size_t)(ch * NC + c) * 128 + b) * 16 + o];
    s += __shfl_xor(s, 16);
    s += __shfl_xor(s, 32);
    __shared__ float red[4][16];
    __shared__ float hred[2];
    if ((t & 63) < 16) red[t >> 6][t & 15] = s;
    __syncthreads();
    if (t < 16) {
        float sum = red[0][t] + red[1][t] + red[2][t] + red[3][t];
        float sq = sum * sum;
#pragma unroll
        for (int d = 1; d < 16; d <<= 1) sq += __shfl_xor(sq, d);
        float vv = sum * sq / ((1.f + sq) * sqrtf(sq));
        int idx = (b * NC + c) * 16 + t;
        v[idx] = vv;
        out[idx] = vv;
        vT[(c * 16 + t) * 128 + b] = vv;
        red[0][t] = vv;
    }
    if (do_head) {
        __syncthreads();
        float partial = 0.f;
        if (t < 100) {
            float hs = b1[c * 100 + t];
#pragma unroll
            for (int i = 0; i < 16; i++) hs = fmaf(red[0][i], w1[(c * 16 + i) * 100 + t], hs);
            partial = tanhf(hs) * w2[c * 100 + t];
        }
#pragma unroll
        for (int d = 1; d < 64; d <<= 1) partial += __shfl_xor(partial, d);
        if ((t & 63) == 0 && t < 128) hred[t >> 6] = partial;
        __syncthreads();
        if (t == 0)
            out[20480 + c * 128 + b] = 1.f / (1.f + expf(-(hred[0] + hred[1] + b2[c])));
    }
}

// a[r,c] = 1/B * sum_{b,o} vT[c,o,b] * sum_i W[r,c,o,i]*xTb[r,b,i];  bij += a
// fp32 W: feedback path into bij logits (bf16 here fails — R14).
__global__ __launch_bounds__(256) void k_a(const unsigned short* __restrict__ xTb,
                                           const float* __restrict__ W,
                                           const float* __restrict__ vT,
                                           float* __restrict__ bij) {
    int wv = threadIdx.x >> 6, lane = threadIdx.x & 63;
    int wid = __builtin_amdgcn_readfirstlane(blockIdx.x * 4 + wv);
    int r = wid / NC, c = wid - r * NC;
    const unsigned short* xr = &xTb[(size_t)r * 1024];
    union { short8 v; unsigned short u[8]; } s0, s1;
    s0.v = *(const short8*)(xr + lane * 8);
    s1.v = *(const short8*)(xr + (lane + 64) * 8);
    float x0[8], x1[8];
#pragma unroll
    for (int i = 0; i < 8; i++) { x0[i] = bf2f(s0.u[i]); x1[i] = bf2f(s1.u[i]); }
    const float* wr = &W[(size_t)r * 1280 + c * 128];
    const float* vc = &vT[c * 2048];
    float acc = 0.f;
#pragma unroll
    for (int o = 0; o < 16; o++) {
        float w[8];
#pragma unroll
        for (int i = 0; i < 8; i++) w[i] = wr[o * 8 + i];
        float u0 = 0.f, u1 = 0.f;
#pragma unroll
        for (int i = 0; i < 8; i++) { u0 = fmaf(w[i], x0[i], u0); u1 = fmaf(w[i], x1[i], u1); }
        acc = fmaf(vc[o * 128 + lane], u0, acc);
        acc = fmaf(vc[o * 128 + lane + 64], u1, acc);
    }
#pragma unroll
    for (int d = 1; d < 64; d <<= 1) acc += __shfl_xor(acc, d);
    if (lane == 0) bij[wid] += acc * 0.0078125f;
}

extern "C" void kernel_launch(void* const* d_in, const int* in_sizes, int n_in,
                              void* d_out, int out_size, void* d_ws, size_t ws_size,
                              hipStream_t stream) {
    const float* data   = (const float*)d_in[0];
    const float* conv_w = (const float*)d_in[1];
    const float* conv_b = (const float*)d_in[2];
    const float* prim_w = (const float*)d_in[3];
    const float* prim_b = (const float*)d_in[4];
    const float* Wd     = (const float*)d_in[5];
    const float* hw1    = (const float*)d_in[6];
    const float* hb1    = (const float*)d_in[7];
    const float* hw2    = (const float*)d_in[8];
    const float* hb2    = (const float*)d_in[9];
    float* ws = (float*)d_ws;
    unsigned short* xh  = (unsigned short*)(ws + OFF_XH);
    float* u0    = ws + OFF_U0;
    unsigned short* xTb = (unsigned short*)(ws + OFF_XTB);
    float* scale = ws + OFF_SC;
    float* bij   = ws + OFF_BIJ;
    float* spart = ws + OFF_SP;
    float* v     = ws + OFF_V;
    unsigned short* Wb  = (unsigned short*)(ws + OFF_WB);
    float* vT    = ws + OFF_VT;
    unsigned short* W1  = (unsigned short*)(ws + OFF_W1);
    float* out = (float*)d_out;

    k_prep<<<787, 256, 0, stream>>>(conv_w, prim_w, W1, Wb, bij, scale);
    k_conv1m<<<128 * 27, 512, 0, stream>>>(data, W1, conv_b, xh);
    k_conv2<<<128 * 5, 512, 0, stream>>>(xh, Wb, prim_b, u0, scale);
    k_xt<<<640, 256, 0, stream>>>(u0, scale, xTb);
    for (int it = 0; it < 3; it++) {
        k_s<<<NCH * NC, 256, 0, stream>>>(xTb, Wd, bij, spart);
        k_v<<<128 * NC, 256, 0, stream>>>(spart, v, vT, out, hw1, hb1, hw2, hb2,
                                          it == 2 ? 1 : 0);
        if (it < 2) k_a<<<5780, 256, 0, stream>>>(xTb, Wd, vT, bij);
    }
}